// Round 14
// baseline (966.276 us; speedup 1.0000x reference)
//
#include <hip/hip_runtime.h>
#include <hip/hip_bf16.h>
#include <cstdint>

// Problem constants (B=4, S=2048, H=2048, I=1024, E=8, K=2)
#define T_TOKENS 8192
#define H_DIM 2048
#define I_DIM 1024
#define N_EXPERTS 8
#define PAIRS (T_TOKENS * 2)
#define TOT_TILES 144            // sum_b ceil(n_b/128) <= 16384/128 + 16
#define TOT_ROWS (TOT_TILES * 128)

using f32x4 = __attribute__((ext_vector_type(4))) float;
using bfv   = __attribute__((ext_vector_type(8))) short;   // MFMA a/b frag (8 bf16)
using u16x8 = __attribute__((ext_vector_type(8))) unsigned short;

typedef __attribute__((address_space(3))) unsigned int lds_u32;
typedef __attribute__((address_space(1))) unsigned int glb_u32;

// async global->LDS, 16B/lane, OFFSET ALWAYS 0 (non-zero imm faulted in r10)
__device__ __forceinline__ void gll16(const void* g, void* l) {
  __builtin_amdgcn_global_load_lds((const glb_u32*)g, (lds_u32*)l, 16, 0, 0);
}
#define SB0() __builtin_amdgcn_sched_barrier(0)
#define BAR() __builtin_amdgcn_s_barrier()

__device__ inline unsigned short f2bf(float f) {
  unsigned int u = __float_as_uint(f);
  u += 0x7FFFu + ((u >> 16) & 1u);          // RTN-even
  return (unsigned short)(u >> 16);
}
__device__ inline float bf2f(unsigned short u) {
  return __uint_as_float((unsigned int)u << 16);
}

// ---------------- fp32 -> bf16 bulk convert (fallback for down_w) ----------------
__global__ __launch_bounds__(256) void moe_convert_kernel(
    const float* __restrict__ src, unsigned short* __restrict__ dst, int n8) {
  int i = blockIdx.x * 256 + threadIdx.x;
  if (i >= n8) return;
  size_t o = (size_t)i * 8;
  f32x4 a = *reinterpret_cast<const f32x4*>(src + o);
  f32x4 b = *reinterpret_cast<const f32x4*>(src + o + 4);
  u16x8 r = {f2bf(a[0]), f2bf(a[1]), f2bf(a[2]), f2bf(a[3]),
             f2bf(b[0]), f2bf(b[1]), f2bf(b[2]), f2bf(b[3])};
  *reinterpret_cast<u16x8*>(dst + o) = r;
}

// ---------------- Router: RMSNorm->logits->softmax->top-2 (fp32) ----------------
// Fused: bf16 copy of X, bf16 conversion of gate/up (+down if W3 non-null).
__global__ __launch_bounds__(256) void moe_router_kernel(
    const float* __restrict__ X, const float* __restrict__ norm_w,
    const float* __restrict__ rw, float* __restrict__ probs,
    float* __restrict__ topw, int* __restrict__ topi,
    unsigned int* __restrict__ counts, unsigned short* __restrict__ Xb,
    const float* __restrict__ gate_w, const float* __restrict__ up_w,
    const float* __restrict__ down_w,
    unsigned short* __restrict__ W1, unsigned short* __restrict__ W2,
    unsigned short* __restrict__ W3) {
  int t = blockIdx.x;
  int tid = threadIdx.x;
  {  // fused weight-convert slice: 2048 floats per block per tensor
    size_t co = (size_t)t * 2048 + tid * 8;
    f32x4 a = *reinterpret_cast<const f32x4*>(gate_w + co);
    f32x4 b = *reinterpret_cast<const f32x4*>(gate_w + co + 4);
    u16x8 r = {f2bf(a[0]), f2bf(a[1]), f2bf(a[2]), f2bf(a[3]),
               f2bf(b[0]), f2bf(b[1]), f2bf(b[2]), f2bf(b[3])};
    *reinterpret_cast<u16x8*>(W1 + co) = r;
    a = *reinterpret_cast<const f32x4*>(up_w + co);
    b = *reinterpret_cast<const f32x4*>(up_w + co + 4);
    u16x8 r2 = {f2bf(a[0]), f2bf(a[1]), f2bf(a[2]), f2bf(a[3]),
                f2bf(b[0]), f2bf(b[1]), f2bf(b[2]), f2bf(b[3])};
    *reinterpret_cast<u16x8*>(W2 + co) = r2;
    if (W3) {
      a = *reinterpret_cast<const f32x4*>(down_w + co);
      b = *reinterpret_cast<const f32x4*>(down_w + co + 4);
      u16x8 r3 = {f2bf(a[0]), f2bf(a[1]), f2bf(a[2]), f2bf(a[3]),
                  f2bf(b[0]), f2bf(b[1]), f2bf(b[2]), f2bf(b[3])};
      *reinterpret_cast<u16x8*>(W3 + co) = r3;
    }
  }
  const float* x = X + (size_t)t * H_DIM;
  int base = tid * 8;
  f32x4 v0 = *reinterpret_cast<const f32x4*>(x + base);
  f32x4 v1 = *reinterpret_cast<const f32x4*>(x + base + 4);
  u16x8 bx = {f2bf(v0[0]), f2bf(v0[1]), f2bf(v0[2]), f2bf(v0[3]),
              f2bf(v1[0]), f2bf(v1[1]), f2bf(v1[2]), f2bf(v1[3])};
  *reinterpret_cast<u16x8*>(Xb + (size_t)t * H_DIM + base) = bx;
  f32x4 nw0 = *reinterpret_cast<const f32x4*>(norm_w + base);
  f32x4 nw1 = *reinterpret_cast<const f32x4*>(norm_w + base + 4);
  float vals[9];
  vals[0] = v0[0]*v0[0] + v0[1]*v0[1] + v0[2]*v0[2] + v0[3]*v0[3]
          + v1[0]*v1[0] + v1[1]*v1[1] + v1[2]*v1[2] + v1[3]*v1[3];
  f32x4 a0 = v0 * nw0, a1 = v1 * nw1;
#pragma unroll
  for (int e = 0; e < 8; ++e) {
    const float* r = rw + e * H_DIM + base;
    f32x4 r0 = *reinterpret_cast<const f32x4*>(r);
    f32x4 r1 = *reinterpret_cast<const f32x4*>(r + 4);
    f32x4 d = a0 * r0 + a1 * r1;
    vals[e + 1] = d[0] + d[1] + d[2] + d[3];
  }
#pragma unroll
  for (int v = 0; v < 9; ++v) {
    float s = vals[v];
#pragma unroll
    for (int off = 32; off > 0; off >>= 1) s += __shfl_xor(s, off);
    vals[v] = s;
  }
  __shared__ float red[4][9];
  int lane = tid & 63, w = tid >> 6;
  if (lane == 0) {
#pragma unroll
    for (int v = 0; v < 9; ++v) red[w][v] = vals[v];
  }
  __syncthreads();
  if (tid == 0) {
    float tot[9];
#pragma unroll
    for (int v = 0; v < 9; ++v) tot[v] = red[0][v] + red[1][v] + red[2][v] + red[3][v];
    float rs = rsqrtf(tot[0] / (float)H_DIM + 1e-6f);
    float lg[8], mx = -1e30f;
#pragma unroll
    for (int e = 0; e < 8; ++e) { lg[e] = tot[e + 1] * rs; mx = fmaxf(mx, lg[e]); }
    float pe[8], sum = 0.f;
#pragma unroll
    for (int e = 0; e < 8; ++e) { pe[e] = expf(lg[e] - mx); sum += pe[e]; }
    float inv = 1.f / sum;
#pragma unroll
    for (int e = 0; e < 8; ++e) { pe[e] *= inv; probs[t * 8 + e] = pe[e]; }
    int b1 = 0; float p1 = pe[0];
#pragma unroll
    for (int e = 1; e < 8; ++e) if (pe[e] > p1) { p1 = pe[e]; b1 = e; }
    int b2 = -1; float p2 = -1.f;
#pragma unroll
    for (int e = 0; e < 8; ++e) if (e != b1 && pe[e] > p2) { p2 = pe[e]; b2 = e; }
    float wsum = p1 + p2;
    topw[t * 2] = p1 / wsum;
    topw[t * 2 + 1] = p2 / wsum;
    topi[t * 2] = b1;
    topi[t * 2 + 1] = b2;
    atomicAdd(&counts[b1], 1u);        // slot-0 bucket
    atomicAdd(&counts[8 + b2], 1u);    // slot-1 bucket
  }
}

// ---------------- importance[e] = sum_t probs[t,e] ----------------
__global__ __launch_bounds__(256) void moe_importance_kernel(
    const float* __restrict__ probs, float* __restrict__ impSum) {
  int e = blockIdx.x, tid = threadIdx.x;
  float s = 0.f;
  for (int t = tid; t < T_TOKENS; t += 256) s += probs[t * 8 + e];
  __shared__ float red[256];
  red[tid] = s;
  __syncthreads();
  for (int st = 128; st > 0; st >>= 1) {
    if (tid < st) red[tid] += red[tid + st];
    __syncthreads();
  }
  if (tid == 0) impSum[e] = red[0];
}

// ---------------- tile offsets + aux loss ----------------
__global__ void moe_offsets_aux_kernel(const unsigned int* __restrict__ counts,
                                       const float* __restrict__ impSum,
                                       int* __restrict__ tileOff,
                                       float* __restrict__ out_aux) {
  if (threadIdx.x == 0 && blockIdx.x == 0) {
    int acc = 0;
    for (int b = 0; b < 16; ++b) {
      tileOff[b] = acc;
      acc += (int)((counts[b] + 127u) >> 7);
    }
    tileOff[16] = acc;
    float a = 0.f;
    for (int e = 0; e < 8; ++e) {
      float load = (float)(counts[e] + counts[8 + e]) / (float)PAIRS;
      a += (impSum[e] / (float)T_TOKENS) * load;
    }
    out_aux[0] = a * (float)N_EXPERTS;
  }
}

// ---------------- bucket pairs (expert x slot) ----------------
__global__ __launch_bounds__(256) void moe_assign_kernel(
    const int* __restrict__ topi, const int* __restrict__ tileOff,
    unsigned int* __restrict__ cursors, int* __restrict__ row2pair) {
  int p = blockIdx.x * 256 + threadIdx.x;
  if (p >= PAIRS) return;
  int b = topi[p] + 8 * (p & 1);
  unsigned int pos = atomicAdd(&cursors[b], 1u);
  row2pair[tileOff[b] * 128 + (int)pos] = p;
}

// ======================= GEMM stages =======================
// r12-proven single-buffer 2-barrier loop (stage 8/12 gll16 -> vmcnt(0) ->
// barrier -> 2 ks x (ds_read + MFMA, setprio) -> barrier).
// LDS rows = 128B, XOR-8 chunk swizzle (0-conflict, proven r2/r9/r12):
//   slot(row,c) = c ^ (row&7); read slot = (ks*4+grp) ^ (lane&7).
// gll16 dest linear (base+lane*16, offset imm 0); 8 adjacent lanes cover one
// row's 128B contiguously (src chunk = (lane&7)^sub) -> fully coalesced.
// NEW (r14): static swizzled grid, 1 item/block, XCD-chunked locality:
//   xcd = blockIdx&7 (dispatch round-robin), chunks of 3 mt x all nt,
//   nt-fastest -> co-resident blocks on an XCD share 3 A-tiles (1.5MB, L2)
//   and sweep B-panels together.

// ---------------- Stage A: P = silu(X@gate^T) * (X@up^T) ----------------
// BM=128, BN=128 B-rows (= 64 I-cols gate|up concat), BK=64, 4 waves 2Mx2N.
// Grid 2304 = 144 mt x 16 nt.
__global__ __launch_bounds__(256, 4) void moe_stage_a(
    const unsigned short* __restrict__ Xb,
    const unsigned short* __restrict__ Wg, const unsigned short* __restrict__ Wu,
    const int* __restrict__ row2pair, const int* __restrict__ tileOff,
    unsigned short* __restrict__ P) {
  __shared__ __align__(16) unsigned short sAB[16384];  // A [0,8192) B [8192,16384)
  __shared__ int sTok[128];
  const int tid = threadIdx.x;
  const int lane = tid & 63, w = tid >> 6;
  const int wm = w >> 1, wn = w & 1;
  const int lrow = lane & 15, grp = lane >> 4;
  const int sub = lane >> 3;
  const int kcs = ((lane & 7) ^ sub) << 3;   // src chunk offset (shorts)
  const int cx = (lane & 7) << 3;            // read-side XOR operand (shorts)
  const int nTiles = tileOff[16];

  // static XCD-chunked decode: b -> (mt, nt); 3mt x 16nt groups per XCD slice
  const int b = blockIdx.x;
  const int xcd = b & 7, j = b >> 3;         // j in [0,288)
  const int grpl = j / 48, r = j % 48;       // 6 groups per XCD
  const int mtl = r >> 4, nt = r & 15;       // nt-fastest (A-tile reuse)
  const int mt = (xcd * 6 + grpl) * 3 + mtl; // in [0,144)
  if (mt >= nTiles) return;

  int bb = 0;
#pragma unroll
  for (int k = 1; k < 16; ++k) if (tileOff[k] <= mt) bb = k;
  const int e = bb & 7;
  const int row0 = mt * 128;
  if (tid < 128) {
    int pr = row2pair[row0 + tid];
    sTok[tid] = (pr >= 0) ? (pr >> 1) : 0;
  }
  __syncthreads();

  const size_t wbase = (size_t)e * ((size_t)I_DIM * H_DIM);
  const unsigned short* src[8];
#pragma unroll
  for (int i = 0; i < 4; ++i) {            // A: row = i*32 + 8w + sub
    int row = i * 32 + 8 * w + sub;
    src[i] = Xb + (size_t)sTok[row] * H_DIM + kcs;
  }
#pragma unroll
  for (int i = 4; i < 8; ++i) {            // B: brow = (i-4)*32 + 8w + sub
    int brow = (i - 4) * 32 + 8 * w + sub;
    int wq = brow >> 6, r6 = brow & 63;
    int ic = nt * 64 + wq * 32 + (r6 & 31);
    const unsigned short* bp = (r6 & 32) ? Wu : Wg;
    src[i] = bp + wbase + (size_t)ic * H_DIM + kcs;
  }

  f32x4 acc[4][4] = {};

#pragma unroll 1
  for (int kk = 0; kk < 32; ++kk) {        // 32 * BK64 = 2048 = H_DIM
#pragma unroll
    for (int i = 0; i < 8; ++i)
      gll16(src[i] + (kk << 6), (void*)&sAB[(i * 256 + tid) * 8]);
    SB0();
    asm volatile("s_waitcnt vmcnt(0)" ::: "memory");
    SB0();
    BAR();
    SB0();
#pragma unroll
    for (int ks = 0; ks < 2; ++ks) {
      const int co = ((ks * 4 + grp) << 3) ^ cx;
      bfv af[4], bf[4];
#pragma unroll
      for (int m = 0; m < 4; ++m)
        af[m] = *reinterpret_cast<const bfv*>(
            &sAB[(wm * 64 + m * 16 + lrow) * 64 + co]);
#pragma unroll
      for (int n = 0; n < 4; ++n)
        bf[n] = *reinterpret_cast<const bfv*>(
            &sAB[8192 + (wn * 64 + n * 16 + lrow) * 64 + co]);
      __builtin_amdgcn_s_setprio(1);
#pragma unroll
      for (int m = 0; m < 4; ++m)
#pragma unroll
        for (int n = 0; n < 4; ++n)
          acc[m][n] = __builtin_amdgcn_mfma_f32_16x16x32_bf16(af[m], bf[n], acc[m][n], 0, 0, 0);
      __builtin_amdgcn_s_setprio(0);
    }
    SB0();
    BAR();
  }

  // epilogue: silu fuse; C/D: row = grp*4+j, col = lrow
#pragma unroll
  for (int m = 0; m < 4; ++m) {
#pragma unroll
    for (int n = 0; n < 2; ++n) {
#pragma unroll
      for (int jj = 0; jj < 4; ++jj) {
        float g = acc[m][n][jj];
        float uu = acc[m][n + 2][jj];
        float pv = (g / (1.f + expf(-g))) * uu;
        int row = row0 + wm * 64 + m * 16 + grp * 4 + jj;
        int col = nt * 64 + wn * 32 + n * 16 + lrow;
        P[(size_t)row * I_DIM + col] = f2bf(pv);
      }
    }
  }
}

// ---------------- Stage B (one-shot): O = P @ down^T -> Opairs (bf16) ----------------
// BM=128, BN=256 H-cols, BK=64, 4 waves (wave tile 64x128, acc[4][8]).
// 12 gll16/thread/K-step; LDS 48KB -> 3 blocks/CU. Grid 1152 = 144 mt x 8 nt.
__global__ __launch_bounds__(256, 3) void moe_stage_b(
    const unsigned short* __restrict__ Pb, const unsigned short* __restrict__ Wd,
    const int* __restrict__ row2pair, const int* __restrict__ tileOff,
    unsigned short* __restrict__ Opairs) {
  __shared__ __align__(16) unsigned short sAB[24576];  // A [0,8192) B [8192,24576)
  __shared__ int sPair[128];
  const int tid = threadIdx.x;
  const int lane = tid & 63, w = tid >> 6;
  const int wm = w >> 1, wn = w & 1;
  const int lrow = lane & 15, grp = lane >> 4;
  const int sub = lane >> 3;
  const int kcs = ((lane & 7) ^ sub) << 3;
  const int cx = (lane & 7) << 3;
  const int nTiles = tileOff[16];

  const int b = blockIdx.x;
  const int xcd = b & 7, j = b >> 3;         // j in [0,144)
  const int grpl = j / 24, r = j % 24;       // 6 groups of 3mt x 8nt
  const int mtl = r >> 3, nt = r & 7;
  const int mt = (xcd * 6 + grpl) * 3 + mtl; // in [0,144)
  if (mt >= nTiles) return;

  int bb = 0;
#pragma unroll
  for (int k = 1; k < 16; ++k) if (tileOff[k] <= mt) bb = k;
  const int e = bb & 7;
  const int row0 = mt * 128, h0 = nt * 256;
  if (tid < 128) sPair[tid] = row2pair[row0 + tid];
  __syncthreads();

  const unsigned short* src[12];
#pragma unroll
  for (int i = 0; i < 4; ++i) {              // A(P): row = i*32 + 8w + sub
    int row = i * 32 + 8 * w + sub;
    src[i] = Pb + (size_t)(row0 + row) * I_DIM + kcs;
  }
#pragma unroll
  for (int i = 4; i < 12; ++i) {             // B(down): brow = (i-4)*32 + 8w + sub
    int brow = (i - 4) * 32 + 8 * w + sub;   // [0,256)
    src[i] = Wd + (size_t)e * ((size_t)H_DIM * I_DIM) + (size_t)(h0 + brow) * I_DIM + kcs;
  }

  f32x4 acc[4][8] = {};

#pragma unroll 1
  for (int kk = 0; kk < 16; ++kk) {          // 16 * BK64 = 1024 = I_DIM
#pragma unroll
    for (int i = 0; i < 12; ++i)
      gll16(src[i] + (kk << 6), (void*)&sAB[(i * 256 + tid) * 8]);
    SB0();
    asm volatile("s_waitcnt vmcnt(0)" ::: "memory");
    SB0();
    BAR();
    SB0();
#pragma unroll
    for (int ks = 0; ks < 2; ++ks) {
      const int co = ((ks * 4 + grp) << 3) ^ cx;
      bfv af[4], bf[8];
#pragma unroll
      for (int m = 0; m < 4; ++m)
        af[m] = *reinterpret_cast<const bfv*>(
            &sAB[(wm * 64 + m * 16 + lrow) * 64 + co]);
#pragma unroll
      for (int n = 0; n < 8; ++n)
        bf[n] = *reinterpret_cast<const bfv*>(
            &sAB[8192 + (wn * 128 + n * 16 + lrow) * 64 + co]);
      __builtin_amdgcn_s_setprio(1);
#pragma unroll
      for (int m = 0; m < 4; ++m)
#pragma unroll
        for (int n = 0; n < 8; ++n)
          acc[m][n] = __builtin_amdgcn_mfma_f32_16x16x32_bf16(af[m], bf[n], acc[m][n], 0, 0, 0);
      __builtin_amdgcn_s_setprio(0);
    }
    SB0();
    BAR();
  }

#pragma unroll
  for (int m = 0; m < 4; ++m) {
#pragma unroll
    for (int jj = 0; jj < 4; ++jj) {
      int rl = wm * 64 + m * 16 + grp * 4 + jj;
      int pr = sPair[rl];
      if (pr < 0) continue;
      unsigned short* orow = Opairs + (size_t)pr * H_DIM + h0 + wn * 128 + lrow;
#pragma unroll
      for (int n = 0; n < 8; ++n) orow[n * 16] = f2bf(acc[m][n][jj]);
    }
  }
}

// ---------------- Combine: out[t] = 4 * (w0*O[2t] + w1*O[2t+1]) ----------------
__global__ __launch_bounds__(256) void moe_combine_kernel(
    const unsigned short* __restrict__ Opairs, const float* __restrict__ topw,
    float* __restrict__ out) {
  size_t g = (size_t)blockIdx.x * 256 + threadIdx.x;
  size_t base = g * 8;
  int t = (int)(base >> 11);
  int h = (int)(base & 2047);
  float w0 = topw[t * 2] * 4.f;
  float w1 = topw[t * 2 + 1] * 4.f;
  u16x8 o0 = *reinterpret_cast<const u16x8*>(Opairs + (size_t)(t * 2) * H_DIM + h);
  u16x8 o1 = *reinterpret_cast<const u16x8*>(Opairs + (size_t)(t * 2 + 1) * H_DIM + h);
  f32x4 r0, r1;
#pragma unroll
  for (int j = 0; j < 4; ++j) r0[j] = w0 * bf2f(o0[j]) + w1 * bf2f(o1[j]);
#pragma unroll
  for (int j = 0; j < 4; ++j) r1[j] = w0 * bf2f(o0[4 + j]) + w1 * bf2f(o1[4 + j]);
  *reinterpret_cast<f32x4*>(out + base) = r0;
  *reinterpret_cast<f32x4*>(out + base + 4) = r1;
}

// ---------------- launch ----------------
// ws layout (bytes), REQ = 138,879,488 (proven); REQ3 = 172,433,920 (gated):
//   P        @ 0           : 18432*1024*2 = 37,748,736
//   probs    @ 37,748,736  : 262,144
//   topw     @ 38,010,880  : 65,536
//   topi     @ 38,076,416  : 65,536
//   row2pair @ 38,141,952  : 73,728
//   ctrl     @ 38,215,680  : 512
//   W1       @ 38,216,192  : 33,554,432  (gate bf16; down bf16 in fallback)
//   W2       @ 71,770,624  : 33,554,432  (up bf16)
//   Xb       @ 105,325,056 : 33,554,432  (X bf16)
//   Opairs   @ 71,770,624  : 67,108,864  (overlays W2+Xb; both dead in stage B)
//   W3       @ 138,879,488 : 33,554,432  (down bf16, only if ws_size >= REQ3)
extern "C" void kernel_launch(void* const* d_in, const int* in_sizes, int n_in,
                              void* d_out, int out_size, void* d_ws, size_t ws_size,
                              hipStream_t stream) {
  const float* X = (const float*)d_in[0];
  const float* norm_w = (const float*)d_in[1];
  const float* router_w = (const float*)d_in[2];
  const float* gate_w = (const float*)d_in[3];
  const float* up_w = (const float*)d_in[4];
  const float* down_w = (const float*)d_in[5];
  float* out = (float*)d_out;

  char* ws = (char*)d_ws;
  unsigned short* P = (unsigned short*)(ws);
  float* probs = (float*)(ws + 37748736);
  float* topw = (float*)(ws + 38010880);
  int* topi = (int*)(ws + 38076416);
  int* row2pair = (int*)(ws + 38141952);
  char* ctrl = ws + 38215680;
  unsigned int* counts = (unsigned int*)(ctrl);
  unsigned int* cursors = (unsigned int*)(ctrl + 64);
  float* impSum = (float*)(ctrl + 128);
  int* tileOff = (int*)(ctrl + 192);
  unsigned short* W1 = (unsigned short*)(ws + 38216192);
  unsigned short* W2 = (unsigned short*)(ws + 71770624);
  unsigned short* Xb = (unsigned short*)(ws + 105325056);
  unsigned short* Opairs = (unsigned short*)(ws + 71770624);
  unsigned short* W3 = (unsigned short*)(ws + 138879488);
  const bool w3ok = ws_size >= 172433920ull;

  hipMemsetAsync(ctrl, 0, 512, stream);
  hipMemsetAsync(row2pair, 0xFF, (size_t)TOT_ROWS * 4, stream);

  moe_router_kernel<<<T_TOKENS, 256, 0, stream>>>(
      X, norm_w, router_w, probs, topw, topi, counts, Xb,
      gate_w, up_w, down_w, W1, W2, w3ok ? W3 : nullptr);
  moe_importance_kernel<<<N_EXPERTS, 256, 0, stream>>>(probs, impSum);
  moe_offsets_aux_kernel<<<1, 64, 0, stream>>>(counts, impSum, tileOff, out + 16777216);
  moe_assign_kernel<<<PAIRS / 256, 256, 0, stream>>>(topi, tileOff, cursors, row2pair);

  moe_stage_a<<<TOT_TILES * 16, 256, 0, stream>>>(Xb, W1, W2, row2pair, tileOff, P);

  const unsigned short* DW = W3;
  if (!w3ok) {
    const int N8 = (N_EXPERTS * I_DIM * H_DIM) / 8;   // 2,097,152
    moe_convert_kernel<<<N8 / 256, 256, 0, stream>>>(down_w, W1, N8);  // gate dead
    DW = W1;
  }
  moe_stage_b<<<TOT_TILES * 8, 256, 0, stream>>>(P, DW, row2pair, tileOff, Opairs);
  moe_combine_kernel<<<T_TOKENS, 256, 0, stream>>>(Opairs, topw, out);
}